// Round 10
// baseline (134.951 us; speedup 1.0000x reference)
//
#include <hip/hip_runtime.h>

// Chamfer distance, B=16, N=M=4096, D=3, fp32.
// v11 INSTRUMENTED ROUND: R9 proved (bit-identical absmax across R7/R8/R9,
// single-variable isolation) that inline-asm v_min3 on MFMA results is a
// corruptor on this toolchain -- BANNED; fminf consumption is the verified
// path. R6's loop (~33us vs ~7us min3 floor) remains unexplained and
// chamfer_mfma sits below the harness's 40us poison-fills in the rocprof
// top-5, so we've been theorizing blind. This round repeats the sweep x4
// in-kernel (idempotent: min over identically-recomputed values; per-rep
// memory fence blocks CSE) to push chamfer to ~110us = top dispatch with
// readable counters. Discriminator:
//   VALUBusy>=90 + MfmaUtil 8-15  => VALU-issue bloat (extracts/movs/fusion)
//   VALUBusy<60 + MfmaUtil<10     => latency/LDS dataflow problem
//   VGPR at cap + dur >> 4x loop  => spill
// Also: launch_bounds(512,6) (85-VGPR budget, removes R6's 64-cap spill
// variable), straight unroll-2 sweep (no rotation math). Numerics = R6
// verbatim (passed, absmax 0.0078). dur_us regression this round is the
// accepted cost; R11 removes REPS and applies the indicated fix.

#define CB 16
#define CN 4096
#define CM 4096
#define WVS 8
#define NQT 4                // query tiles (of 16) per wave
#define QPW (NQT * 16)       // 64 queries per wave
#define QPB (WVS * QPW)      // 512 queries per block
#define TPB 512              // targets per block
#define NTT (TPB / 16)       // 32 target tiles
#define REPS 4               // instrumentation: sweep repeat (idempotent)

typedef float f32x4 __attribute__((ext_vector_type(4)));
typedef short bf16x8 __attribute__((ext_vector_type(8)));
typedef unsigned int u32;
typedef u32 u32x4 __attribute__((ext_vector_type(4)));

__device__ __forceinline__ u32 f2bf(float f) {          // RNE f32 -> bf16 bits
    u32 u = __float_as_uint(f);
    return (u + 0x7FFFu + ((u >> 16) & 1u)) >> 16;
}
__device__ __forceinline__ float bf2f(u32 h) { return __uint_as_float(h << 16); }

__global__ void init_out(unsigned* __restrict__ out)
{
    out[blockIdx.x * 512 + threadIdx.x] = 0x7F800000u;  // +inf bits
}

// grid: (8 qtiles x 8 tchunks, 16 batches, 2 dirs) = 2048 blocks x 512 thr.
__global__ __launch_bounds__(512, 6) void chamfer_mfma(
    const float* __restrict__ x1, const float* __restrict__ x2,
    unsigned* __restrict__ out)
{
    const int dir    = blockIdx.z;
    const int b      = blockIdx.y;
    const int qtile  = blockIdx.x & 7;   // 512-query tile
    const int tchunk = blockIdx.x >> 3;  // 512-target chunk

    const float* __restrict__ qraw = (dir ? x2 : x1) + (size_t)b * CN * 3;
    const float* __restrict__ traw = (dir ? x1 : x2) + (size_t)b * CM * 3
                                   + (size_t)tchunk * TPB * 3;
    unsigned* __restrict__ o = out + (dir ? ((size_t)CB * CN + (size_t)b * CM)
                                          : ((size_t)b * CN)) + qtile * QPB;

    // [tile][64]: lanes 0-15 kb0 records, 16-31 kb1, 32-63 zeros. 32 KB.
    __shared__ u32x4 AI[NTT * 64];

    const int tid  = threadIdx.x;
    const int lane = tid & 63;
    const int wave = __builtin_amdgcn_readfirstlane(tid >> 6);
    const int row  = lane & 15;
    const int kb   = lane >> 4;

    // ---- Stage: thread tid packs target tid (1 per thread, branch-free).
    {
        const float* tp3 = traw + 3 * tid;
        float X = tp3[0], Y = tp3[1], Z = tp3[2];
        u32 xh = f2bf(X), yh = f2bf(Y), zh = f2bf(Z);
        u32 xl = f2bf(X - bf2f(xh));
        u32 yl = f2bf(Y - bf2f(yh));
        u32 zl = f2bf(Z - bf2f(zh));
        float nt = fmaf(X, X, fmaf(Y, Y, Z * Z));
        u32 nh = f2bf(nt), nl = f2bf(nt - bf2f(nh));
        const int base = (tid >> 4) * 64 + (tid & 15);
        AI[base +  0] = (u32x4){xh | (yh << 16), zh | (xl << 16),
                                yl | (zl << 16), xh | (yh << 16)};
        AI[base + 16] = (u32x4){zh | (nh << 16), nl, 0u, 0u};
        AI[base + 32] = (u32x4){0u, 0u, 0u, 0u};
        AI[base + 48] = (u32x4){0u, 0u, 0u, 0u};
    }

    // ---- Queries: wave covers [qtile*512 + wave*64, +64); lane's col = row.
    // B-frag kb0: {mhx,mhy | mhz,mhx | mhy,mhz | mlx,mly}
    //        kb1: {mlz,1.0 | 1.0,0 | 0,0 | 0,0}; kb>=2 zero.  (m = -2q)
    bf16x8 bq[NQT];
    float nq[NQT];
    #pragma unroll
    for (int qt = 0; qt < NQT; ++qt) {
        const float* qp = qraw
            + (size_t)3 * (qtile * QPB + wave * QPW + qt * 16 + row);
        float qx = qp[0], qy = qp[1], qz = qp[2];
        nq[qt] = fmaf(qx, qx, fmaf(qy, qy, qz * qz));
        float MX = -2.f * qx, MY = -2.f * qy, MZ = -2.f * qz;
        u32 xh = f2bf(MX), yh = f2bf(MY), zh = f2bf(MZ);
        u32 xl = f2bf(MX - bf2f(xh));
        u32 yl = f2bf(MY - bf2f(yh));
        u32 zl = f2bf(MZ - bf2f(zh));
        u32x4 w;
        if (kb == 0)
            w = (u32x4){xh | (yh << 16), zh | (xh << 16),
                        yh | (zh << 16), xl | (yl << 16)};
        else if (kb == 1)
            w = (u32x4){zl | (0x3F80u << 16), 0x3F80u, 0u, 0u};
        else
            w = (u32x4){0u, 0u, 0u, 0u};
        bq[qt] = __builtin_bit_cast(bf16x8, w);
    }

    float best0[NQT], best1[NQT];
    #pragma unroll
    for (int qt = 0; qt < NQT; ++qt) { best0[qt] = 1e30f; best1[qt] = 1e30f; }

    __syncthreads();

    // ---- Sweep 32 tiles (x REPS for instrumentation; min is idempotent).
    const u32x4* ap = &AI[lane];
    #pragma unroll 1
    for (int rep = 0; rep < REPS; ++rep) {
        asm volatile("" ::: "memory");   // block cross-rep LDS-value CSE
        #pragma unroll 1
        for (int t = 0; t < NTT; t += 2) {
            #pragma unroll
            for (int u = 0; u < 2; ++u) {
                bf16x8 af = __builtin_bit_cast(bf16x8, ap[(t + u) * 64]);
                #pragma unroll
                for (int qt = 0; qt < NQT; ++qt) {
                    f32x4 acc = __builtin_amdgcn_mfma_f32_16x16x32_bf16(
                        af, bq[qt], (f32x4){0.f, 0.f, 0.f, 0.f}, 0, 0, 0);
                    best0[qt] = fminf(fminf(best0[qt], acc.x), acc.y);
                    best1[qt] = fminf(fminf(best1[qt], acc.z), acc.w);
                }
            }
        }
    }

    // ---- Reduce kb groups (rows 0-15 per tile), add |q|^2, clamp, merge.
    #pragma unroll
    for (int qt = 0; qt < NQT; ++qt) {
        float v = fminf(best0[qt], best1[qt]);
        v = fminf(v, __shfl_xor(v, 16));
        v = fminf(v, __shfl_xor(v, 32));
        if (kb == 0) {
            float val = fmaxf(v + nq[qt], 0.f);
            atomicMin(o + wave * QPW + qt * 16 + row, __float_as_uint(val));
        }
    }
}

extern "C" void kernel_launch(void* const* d_in, const int* in_sizes, int n_in,
                              void* d_out, int out_size, void* d_ws, size_t ws_size,
                              hipStream_t stream) {
    const float* x1 = (const float*)d_in[0];   // [B,N,3]
    const float* x2 = (const float*)d_in[1];   // [B,M,3]
    unsigned* out = (unsigned*)d_out;

    init_out<<<dim3(2 * CB * CN / 512), 512, 0, stream>>>(out);
    chamfer_mfma<<<dim3(64, CB, 2), 512, 0, stream>>>(x1, x2, out);
}

// Round 11
// 96.154 us; speedup vs baseline: 1.4035x; 1.4035x over previous
//
#include <hip/hip_runtime.h>

// Chamfer distance, B=16, N=M=4096, D=3, fp32.
// v12: R10's instrumented counters closed the model: VALUBusy 59.6% observed
// vs 59.3% predicted from 16 v_min/tile @ 4 cyc => the loop cost IS the
// min-reduction (1 v_min per element); MFMA real duty ~18% (65% MfmaUtil is
// gfx94x-formula inflation); 0 bank conflicts; loop 19.7us/rep + 13.4us
// prologue/launch overhead. Three targeted fixes:
//  (1) 0.75 min-ops/element: p=fminf(acc.x,acc.y), r=fminf(acc.z,acc.w)
//      (compiler-emitted v_min consuming MFMA results -- the R4/R6-proven
//      hazard-safe path), then ONE asm v_min3(best,p,r) whose inputs are
//      exclusively VALU results. R9 isolated the corruptor class as asm
//      reading MFMA-DEST regs; asm-min3 on VALU values passed in R0-R2.
//  (2) R8's perm/truncation bf16 packing for the prologue (~half the VALU;
//      packing verified term-by-term -- R8's failure was its asm, not this).
//  (3) compact LDS: no materialized zero rows; kb>=2 lanes read a shared
//      512B zero block. 32.5 -> 16.9 KB => 4 blocks/CU resident.
// Numerics: d = |t|^2 - 2 t.q via K=11 bf16 hi/lo (trunc split: hi=trunc,
// lo=trunc(x-hi); dropped tl*ml + lo-of-lo ~ 2^-16 rel). A word w and B
// word w use pack2 with positionally-matched args so the halfword order
// cancels in the dot product. K0-7 A:{(X,Y),(Z,xl),(yl,zl),(X,Y)} B:
// {(MX,MY),(MZ,MX),(MY,MZ),(mxl,myl)}; K8-15 A:{(Z,nt),(ntl,0),0,0} B:
// {(mzl,1),(1,0),0,0}; kb>=2 af=0. |q|^2 added in fp32 epilogue.
// C/D map (m89): col=lane&15, row=(lane>>4)*4+reg; all 64 lanes hold valid
// output rows -> shfl_xor(16,32) min + lanes 0-15 write. Partial mins
// across 8 target-chunks merged via monotone uint atomicMin (vals >= 0)
// into +inf-prefilled out.

#define CB 16
#define CN 4096
#define CM 4096
#define WVS 8
#define NQT 4                // query tiles (of 16) per wave
#define QPW (NQT * 16)       // 64 queries per wave
#define QPB (WVS * QPW)      // 512 queries per block
#define TPB 512              // targets per block
#define NTT (TPB / 16)       // 32 target tiles
#define ZOFF (NTT * 32)      // zero-block offset (u32x4 units)

typedef float f32x4 __attribute__((ext_vector_type(4)));
typedef short bf16x8 __attribute__((ext_vector_type(8)));
typedef unsigned int u32;
typedef u32 u32x4 __attribute__((ext_vector_type(4)));

// pack2(a,b): one halfword = bf16_trunc(a), other = bf16_trunc(b); order is
// convention-dependent but used positionally-matched on A and B sides.
__device__ __forceinline__ u32 pack2(float a, float b) {
    return __builtin_amdgcn_perm(__float_as_uint(b), __float_as_uint(a),
                                 0x07060302u);
}
__device__ __forceinline__ float hi_f(float a) {     // bf16_trunc as f32
    return __uint_as_float(__float_as_uint(a) & 0xFFFF0000u);
}

__global__ void init_out(unsigned* __restrict__ out)
{
    out[blockIdx.x * 512 + threadIdx.x] = 0x7F800000u;  // +inf bits
}

// grid: (8 qtiles x 8 tchunks, 16 batches, 2 dirs) = 2048 blocks x 512 thr.
__global__ __launch_bounds__(512, 8) void chamfer_mfma(
    const float* __restrict__ x1, const float* __restrict__ x2,
    unsigned* __restrict__ out)
{
    const int dir    = blockIdx.z;
    const int b      = blockIdx.y;
    const int qtile  = blockIdx.x & 7;   // 512-query tile
    const int tchunk = blockIdx.x >> 3;  // 512-target chunk

    const float* __restrict__ qraw = (dir ? x2 : x1) + (size_t)b * CN * 3;
    const float* __restrict__ traw = (dir ? x1 : x2) + (size_t)b * CM * 3
                                   + (size_t)tchunk * TPB * 3;
    unsigned* __restrict__ o = out + (dir ? ((size_t)CB * CN + (size_t)b * CM)
                                          : ((size_t)b * CN)) + qtile * QPB;

    // Compact: 32 tiles x 32 u32x4 (lanes 0-15 word0, 16-31 word1) + 32-entry
    // zero block for kb>=2 lanes. 16.9 KB.
    __shared__ u32x4 AI[ZOFF + 32];

    const int tid  = threadIdx.x;
    const int lane = tid & 63;
    const int wave = __builtin_amdgcn_readfirstlane(tid >> 6);
    const int row  = lane & 15;
    const int kb   = lane >> 4;

    // ---- Stage: thread tid packs target tid (1 per thread, branch-free).
    {
        const float* tp3 = traw + 3 * tid;
        float X = tp3[0], Y = tp3[1], Zc = tp3[2];
        float xl = X - hi_f(X);
        float yl = Y - hi_f(Y);
        float zl = Zc - hi_f(Zc);
        float nt = fmaf(X, X, fmaf(Y, Y, Zc * Zc));
        float ntl = nt - hi_f(nt);
        const int base = (tid >> 4) * 32 + (tid & 15);
        AI[base +  0] = (u32x4){pack2(X, Y), pack2(Zc, xl),
                                pack2(yl, zl), pack2(X, Y)};
        AI[base + 16] = (u32x4){pack2(Zc, nt), pack2(ntl, 0.f), 0u, 0u};
    }
    if (tid < 32) AI[ZOFF + tid] = (u32x4){0u, 0u, 0u, 0u};

    // ---- Queries: wave covers [qtile*512 + wave*64, +64); lane's col = row.
    bf16x8 bq[NQT];
    float nq[NQT];
    #pragma unroll
    for (int qt = 0; qt < NQT; ++qt) {
        const float* qp = qraw
            + (size_t)3 * (qtile * QPB + wave * QPW + qt * 16 + row);
        float qx = qp[0], qy = qp[1], qz = qp[2];
        nq[qt] = fmaf(qx, qx, fmaf(qy, qy, qz * qz));
        float MX = -2.f * qx, MY = -2.f * qy, MZ = -2.f * qz;
        float mxl = MX - hi_f(MX);
        float myl = MY - hi_f(MY);
        float mzl = MZ - hi_f(MZ);
        u32x4 w;
        if (kb == 0)
            w = (u32x4){pack2(MX, MY), pack2(MZ, MX),
                        pack2(MY, MZ), pack2(mxl, myl)};
        else if (kb == 1)
            w = (u32x4){pack2(mzl, 1.0f), pack2(1.0f, 0.f), 0u, 0u};
        else
            w = (u32x4){0u, 0u, 0u, 0u};
        bq[qt] = __builtin_bit_cast(bf16x8, w);
    }

    float best[NQT];
    #pragma unroll
    for (int qt = 0; qt < NQT; ++qt) best[qt] = 1e30f;

    __syncthreads();

    // ---- Sweep 32 tiles: 1 ds_read_b128 (lanes 0-31 tile data, 32-63 zero
    // block; contiguous, conflict-free) + 4 MFMA + 8 v_min + 4 asm v_min3.
    // The asm min3 reads ONLY VALU results (p, r, best) -- never MFMA dests.
    u32 idx = (lane < 32) ? (u32)lane : (u32)(ZOFF + (lane - 32));
    const u32 step = (lane < 32) ? 32u : 0u;
    #pragma unroll 1
    for (int t = 0; t < NTT; t += 2) {
        #pragma unroll
        for (int u = 0; u < 2; ++u) {
            bf16x8 af = __builtin_bit_cast(bf16x8, AI[idx]);
            idx += step;
            #pragma unroll
            for (int qt = 0; qt < NQT; ++qt) {
                f32x4 acc = __builtin_amdgcn_mfma_f32_16x16x32_bf16(
                    af, bq[qt], (f32x4){0.f, 0.f, 0.f, 0.f}, 0, 0, 0);
                float p = fminf(acc.x, acc.y);   // compiler v_min (hazard-safe)
                float r = fminf(acc.z, acc.w);   // compiler v_min
                float nb;
                asm("v_min3_f32 %0, %1, %2, %3"
                    : "=v"(nb) : "v"(best[qt]), "v"(p), "v"(r));
                best[qt] = nb;
            }
        }
    }

    // ---- All 64 lanes hold valid C rows: combine row-groups, add |q|^2,
    // clamp, atomic-merge the 8 target chunks.
    #pragma unroll
    for (int qt = 0; qt < NQT; ++qt) {
        float v = best[qt];
        v = fminf(v, __shfl_xor(v, 16));
        v = fminf(v, __shfl_xor(v, 32));
        if (kb == 0) {
            float val = fmaxf(v + nq[qt], 0.f);
            atomicMin(o + wave * QPW + qt * 16 + row, __float_as_uint(val));
        }
    }
}

extern "C" void kernel_launch(void* const* d_in, const int* in_sizes, int n_in,
                              void* d_out, int out_size, void* d_ws, size_t ws_size,
                              hipStream_t stream) {
    const float* x1 = (const float*)d_in[0];   // [B,N,3]
    const float* x2 = (const float*)d_in[1];   // [B,M,3]
    unsigned* out = (unsigned*)d_out;

    init_out<<<dim3(2 * CB * CN / 512), 512, 0, stream>>>(out);
    chamfer_mfma<<<dim3(64, CB, 2), 512, 0, stream>>>(x1, x2, out);
}

// Round 12
// 78.086 us; speedup vs baseline: 1.7282x; 1.2314x over previous
//
#include <hip/hip_runtime.h>

// Chamfer distance, B=16, N=M=4096, D=3, fp32.
// v13: R11 measured chamfer directly (47.4us): the asm v_min3 was correct
// but DEOPTIMIZING (+350 movs/wave, broke MFMA/VALU interleave) => NO
// inline asm anywhere (R7-9: corrupts reading MFMA dests; R11: slows even
// on VALU inputs). Pure-fminf loop (R6/R10-verified: exactly 1 v_min per
// element, optimally scheduled). Floor: 8192 wave-mins/SIMD x 4cyc=13.7us.
// R6's extra ~19us was replicated prologue (2048 blocks: query packs x8,
// init_out+atomics) -- so v13 restructures:
//  - 512 blocks = 16 qtiles x 16 batches x 2 dirs; block sweeps ALL 4096
//    targets via 2 LDS chunks of 2048 (64KB, 2 blocks/CU, 4 waves/SIMD;
//    R2 proved issue saturation at 2.4 waves/SIMD).
//  - block owns its 256 queries fully => direct stores, NO atomicMin, NO
//    init_out, single launch. Query pack 1x (was 8x).
//  - no zero-block: lanes 32-63 mirror lanes 0-31's LDS reads; their
//    garbage A-frags hit B's kb>=2 ZERO fragments (finite*0=0). Saves LDS
//    and the pad writes.
//  - NQT=2: one ds_read_b128 feeds 2 MFMA; unroll-4 tile loop (imm offsets).
// Numerics = R11 (passed, absmax 0.0078): K=11 bf16 hi/lo trunc splits,
// pack2 (v_perm) positionally matched on A and B so halfword order cancels.
// A kb0:{(X,Y),(Z,xl),(yl,zl),(X,Y)} kb1:{(Z,nt),(ntl,0),0,0};
// B kb0:{(MX,MY),(MZ,MX),(MY,MZ),(mxl,myl)} kb1:{(mzl,1),(1,0),0,0}, M=-2q.
// C/D map (m89): col=lane&15, row=(lane>>4)*4+reg; shfl_xor(16,32) min
// combines the 4 row-groups; lanes kb==0 store 16 queries per qt.

#define CB 16
#define CN 4096
#define CM 4096
#define WVS 8
#define NQT 2                // query tiles (of 16) per wave
#define QPW (NQT * 16)       // 32 queries per wave
#define QPB (WVS * QPW)      // 256 queries per block
#define TPC 2048             // targets per LDS chunk
#define NCH (CM / TPC)       // 2 chunks
#define NTT (TPC / 16)       // 128 tiles per chunk

typedef float f32x4 __attribute__((ext_vector_type(4)));
typedef short bf16x8 __attribute__((ext_vector_type(8)));
typedef unsigned int u32;
typedef u32 u32x4 __attribute__((ext_vector_type(4)));
typedef float v4f __attribute__((ext_vector_type(4)));

// pack2(a,b): halfwords = bf16_trunc(a), bf16_trunc(b); order is
// convention-dependent but positionally matched on A and B sides, so it
// cancels in the dot product. (R11-verified.)
__device__ __forceinline__ u32 pack2(float a, float b) {
    return __builtin_amdgcn_perm(__float_as_uint(b), __float_as_uint(a),
                                 0x07060302u);
}
__device__ __forceinline__ float hi_f(float a) {     // bf16_trunc as f32
    return __uint_as_float(__float_as_uint(a) & 0xFFFF0000u);
}

// grid: (16 qtiles, 16 batches, 2 dirs) = 512 blocks x 512 thr, single launch.
__global__ __launch_bounds__(512, 4) void chamfer_mfma(
    const float* __restrict__ x1, const float* __restrict__ x2,
    float* __restrict__ out)
{
    const int dir   = blockIdx.z;
    const int b     = blockIdx.y;
    const int qtile = blockIdx.x;        // 256-query tile

    const float* __restrict__ qraw = (dir ? x2 : x1) + (size_t)b * CN * 3;
    const float* __restrict__ traw = (dir ? x1 : x2) + (size_t)b * CM * 3;
    float* __restrict__ o = out + (dir ? ((size_t)CB * CN + (size_t)b * CM)
                                       : ((size_t)b * CN)) + qtile * QPB;

    // [tile][32]: entries 0-15 = word0 (K0-7) rows, 16-31 = word1 (K8-15).
    __shared__ u32x4 AI[NTT * 32];       // 64 KB exactly

    const int tid  = threadIdx.x;
    const int lane = tid & 63;
    const int wave = __builtin_amdgcn_readfirstlane(tid >> 6);
    const int col  = lane & 15;          // C column = query index
    const int kb   = lane >> 4;

    // ---- Queries (once per block): wave covers [qtile*256 + wave*32, +32).
    bf16x8 bq[NQT];
    float nq[NQT];
    #pragma unroll
    for (int qt = 0; qt < NQT; ++qt) {
        const float* qp = qraw
            + (size_t)3 * (qtile * QPB + wave * QPW + qt * 16 + col);
        float qx = qp[0], qy = qp[1], qz = qp[2];
        nq[qt] = fmaf(qx, qx, fmaf(qy, qy, qz * qz));
        float MX = -2.f * qx, MY = -2.f * qy, MZ = -2.f * qz;
        float mxl = MX - hi_f(MX);
        float myl = MY - hi_f(MY);
        float mzl = MZ - hi_f(MZ);
        u32x4 w;
        if (kb == 0)
            w = (u32x4){pack2(MX, MY), pack2(MZ, MX),
                        pack2(MY, MZ), pack2(mxl, myl)};
        else if (kb == 1)
            w = (u32x4){pack2(mzl, 1.0f), pack2(1.0f, 0.f), 0u, 0u};
        else
            w = (u32x4){0u, 0u, 0u, 0u};
        bq[qt] = __builtin_bit_cast(bf16x8, w);
    }

    float best0[NQT], best1[NQT];
    #pragma unroll
    for (int qt = 0; qt < NQT; ++qt) { best0[qt] = 1e30f; best1[qt] = 1e30f; }

    const int lsel = lane & 31;          // lanes 32-63 mirror 0-31 (B zeros
                                         // null their A garbage: finite*0=0)
    #pragma unroll 1
    for (int c = 0; c < NCH; ++c) {
        // ---- Stage chunk c: thread packs targets [4*tid, 4*tid+4).
        {
            const v4f* rv = (const v4f*)(traw + (size_t)(c * TPC + 4 * tid) * 3);
            v4f r0 = rv[0], r1 = rv[1], r2 = rv[2];
            // r0=(t0x,t0y,t0z,t1x) r1=(t1y,t1z,t2x,t2y) r2=(t2z,t3x,t3y,t3z)
            const float tx[4] = {r0.x, r0.w, r1.z, r2.y};
            const float ty[4] = {r0.y, r1.x, r1.w, r2.z};
            const float tz[4] = {r0.z, r1.y, r2.x, r2.w};
            #pragma unroll
            for (int i = 0; i < 4; ++i) {
                float X = tx[i], Y = ty[i], Zc = tz[i];
                float xl = X - hi_f(X);
                float yl = Y - hi_f(Y);
                float zl = Zc - hi_f(Zc);
                float nt = fmaf(X, X, fmaf(Y, Y, Zc * Zc));
                float ntl = nt - hi_f(nt);
                const int r = 4 * tid + i;                 // chunk-local idx
                const int base = (r >> 4) * 32 + (r & 15);
                AI[base +  0] = (u32x4){pack2(X, Y), pack2(Zc, xl),
                                        pack2(yl, zl), pack2(X, Y)};
                AI[base + 16] = (u32x4){pack2(Zc, nt), pack2(ntl, 0.f),
                                        0u, 0u};
            }
        }
        __syncthreads();

        // ---- Sweep 128 tiles: 1 ds_read_b128 (512B stride, 2-way same-addr
        // broadcast for the mirrored half = free) + 2 MFMA + 8 v_min.
        #pragma unroll 1
        for (int t = 0; t < NTT; t += 4) {
            #pragma unroll
            for (int u = 0; u < 4; ++u) {
                bf16x8 af = __builtin_bit_cast(bf16x8, AI[(t + u) * 32 + lsel]);
                #pragma unroll
                for (int qt = 0; qt < NQT; ++qt) {
                    f32x4 acc = __builtin_amdgcn_mfma_f32_16x16x32_bf16(
                        af, bq[qt], (f32x4){0.f, 0.f, 0.f, 0.f}, 0, 0, 0);
                    best0[qt] = fminf(fminf(best0[qt], acc.x), acc.y);
                    best1[qt] = fminf(fminf(best1[qt], acc.z), acc.w);
                }
            }
        }
        __syncthreads();   // before next chunk overwrites LDS
    }

    // ---- Combine the 4 row-groups, add |q|^2, clamp, direct store.
    #pragma unroll
    for (int qt = 0; qt < NQT; ++qt) {
        float v = fminf(best0[qt], best1[qt]);
        v = fminf(v, __shfl_xor(v, 16));
        v = fminf(v, __shfl_xor(v, 32));
        if (kb == 0)
            o[wave * QPW + qt * 16 + col] = fmaxf(v + nq[qt], 0.f);
    }
}

extern "C" void kernel_launch(void* const* d_in, const int* in_sizes, int n_in,
                              void* d_out, int out_size, void* d_ws, size_t ws_size,
                              hipStream_t stream) {
    const float* x1 = (const float*)d_in[0];   // [B,N,3]
    const float* x2 = (const float*)d_in[1];   // [B,M,3]
    float* out = (float*)d_out;

    chamfer_mfma<<<dim3(16, CB, 2), 512, 0, stream>>>(x1, x2, out);
}